// Round 17
// baseline (267.262 us; speedup 1.0000x reference)
//
#include <hip/hip_runtime.h>

#define M_DIM 16384
#define N_DIM 1024
#define K_DIM 4096

#define BM 256
#define BN 256
#define BK 64
#define NT (K_DIM / BK)

typedef __attribute__((ext_vector_type(4))) float f32x4;
typedef __attribute__((ext_vector_type(8))) short bf16x8;
typedef __attribute__((ext_vector_type(8))) unsigned short u16x8;

static __device__ __forceinline__ short f2bf(float f) {
  union { __bf16 h; short s; } u;
  u.h = (__bf16)f;   // RNE; pairs pack into v_cvt_pk_bf16_f32
  return u.s;
}

static __device__ __forceinline__ void load_lds16(const void* g, void* l) {
  __builtin_amdgcn_global_load_lds(
      (const __attribute__((address_space(1))) void*)g,
      (__attribute__((address_space(3))) void*)l, 16, 0, 0);
}

// ---------- prepass: WbT[n][k] = bf16(sign(W[k][n])) ----------
// Row stride 70 u16 (35 dwords): column reads split across 2 bank sets,
// worst 2-way alias (free, m136).
__global__ __launch_bounds__(256) void wsign_transpose(
    const float* __restrict__ W, unsigned short* __restrict__ WbT) {
  __shared__ unsigned short tile[64][70];
  const int t  = (int)threadIdx.x;
  const int k0 = (int)(blockIdx.x >> 4) * 64;
  const int n0 = (int)(blockIdx.x & 15) * 64;
#pragma unroll
  for (int p = 0; p < 4; ++p) {
    const int r = p * 16 + (t >> 4);
    const int c = (t & 15) * 4;
    const float* src = W + (size_t)(k0 + r) * N_DIM + n0 + c;
#pragma unroll
    for (int j = 0; j < 4; ++j) {
      const float w = src[j];
      tile[r][c + j] = (w > 0.f) ? (unsigned short)0x3F80u
                                 : ((w < 0.f) ? (unsigned short)0xBF80u
                                              : (unsigned short)0u);
    }
  }
  __syncthreads();
  const int n  = t >> 2;
  const int kg = (t & 3) * 16;
  u16x8 o0, o1;
#pragma unroll
  for (int j = 0; j < 8; ++j) o0[j] = tile[kg + j][n];
#pragma unroll
  for (int j = 0; j < 8; ++j) o1[j] = tile[kg + 8 + j][n];
  unsigned short* dst = WbT + (size_t)(n0 + n) * K_DIM + k0 + kg;
  *(u16x8*)dst       = o0;
  *(u16x8*)(dst + 8) = o1;
}

// ---------- main GEMM: R16 counted-lgkm pipeline, x2-unrolled ----------
// Steady loop processes 2 tiles/iteration with LITERAL buffer indices
// (ds_read offsets fold to immediates). PH3's vmcnt(8) moved after the
// MFMA cluster (still before the publish barrier) so B-DMA completion
// overlaps the MFMA burst. All counts/order otherwise identical to R16.
__global__ __launch_bounds__(512, 2) void gemm_r17(
    const float* __restrict__ X, const unsigned short* __restrict__ WbT,
    const float* __restrict__ bias, float* __restrict__ Z) {
  __shared__ __align__(16) unsigned short As[2][BM * BK];  // 64 KiB
  __shared__ __align__(16) unsigned short Bs[2][BN * BK];  // 64 KiB

  const int t   = (int)threadIdx.x;
  const int l   = t & 63;
  const int wid = t >> 6;
  const int wm  = wid >> 2;  // 0..1
  const int wn  = wid & 3;   // 0..3

  const int bid = (int)blockIdx.x;
  const int swz = (bid & 7) * 32 + (bid >> 3);  // bijective: 256 = 8*32
  const int m0  = (swz >> 2) * BM;
  const int n0  = (swz & 3) * BN;

  const int abase = (wm * 128 + (l & 15)) * BK;
  const int bbase = (wn * 64 + (l & 15)) * BK;
  const int axk0  = (((l >> 4) + 0) ^ (l & 7)) << 3;
  const int axk1  = (((l >> 4) + 4) ^ (l & 7)) << 3;

  // A staging: thread owns rows {i*64 + t>>3}, k-granule t&7
  const float* sA0 = X + (size_t)(m0 +   0 + (t >> 3)) * K_DIM + (t & 7) * 8;
  const float* sA1 = X + (size_t)(m0 +  64 + (t >> 3)) * K_DIM + (t & 7) * 8;
  const float* sA2 = X + (size_t)(m0 + 128 + (t >> 3)) * K_DIM + (t & 7) * 8;
  const float* sA3 = X + (size_t)(m0 + 192 + (t >> 3)) * K_DIM + (t & 7) * 8;
  const int adst = (t >> 3) * BK + (((t & 7) ^ ((t >> 3) & 7)) << 3);

  // B staging: linear LDS dest, inverse-swizzled global source
  const unsigned short* b_src[4];
  int b_dst[4];
#pragma unroll
  for (int i = 0; i < 4; ++i) {
    const int c = i * 512 + t;
    const int n = c >> 3, gp = c & 7;
    b_src[i] = WbT + (size_t)(n0 + n) * K_DIM + (gp ^ (n & 7)) * 8;
    b_dst[i] = c * 8;
  }

  f32x4 acc[8][4] = {};      // 128 acc regs
  f32x4 ar[4][2];            // A(t+1) staging (32)
  bf16x8 a0F[4], a1F[4];     // ping/pong A frags (16+16)
  bf16x8 b0F[4], b1F[4];     // kk0 / kk1 B frags (16+16)

#define SB0 __builtin_amdgcn_sched_barrier(0)
#define BAR do { SB0; __builtin_amdgcn_s_barrier(); SB0; } while (0)
#define WVM(N) do { asm volatile("s_waitcnt vmcnt(" #N ")" ::: "memory"); SB0; } while (0)
#define WLG(N) do { asm volatile("s_waitcnt lgkmcnt(" #N ")" ::: "memory"); SB0; } while (0)

#define LD_A8(KT)                                                          \
  do { SB0;                                                                \
    ar[0][0] = *(const f32x4*)(sA0 + (KT));                                \
    ar[0][1] = *(const f32x4*)(sA0 + (KT) + 4);                            \
    ar[1][0] = *(const f32x4*)(sA1 + (KT));                                \
    ar[1][1] = *(const f32x4*)(sA1 + (KT) + 4);                            \
    ar[2][0] = *(const f32x4*)(sA2 + (KT));                                \
    ar[2][1] = *(const f32x4*)(sA2 + (KT) + 4);                            \
    ar[3][0] = *(const f32x4*)(sA3 + (KT));                                \
    ar[3][1] = *(const f32x4*)(sA3 + (KT) + 4); SB0;                       \
  } while (0)
#define WR_AH(BUF, H)                                                      \
  do { SB0;                                                                \
    _Pragma("unroll") for (int j = 2 * (H); j < 2 * (H) + 2; ++j) {        \
      u16x8 v;                                                             \
      _Pragma("unroll") for (int q = 0; q < 4; ++q) {                      \
        v[q]     = (unsigned short)f2bf(ar[j][0][q]);                      \
        v[4 + q] = (unsigned short)f2bf(ar[j][1][q]);                      \
      }                                                                    \
      *(u16x8*)(&As[BUF][adst + j * 4096]) = v;                            \
    } SB0;                                                                 \
  } while (0)
#define DMA_B4(KT, BUF)                                                    \
  do { SB0;                                                                \
    _Pragma("unroll") for (int i = 0; i < 4; ++i)                          \
      load_lds16(b_src[i] + (KT), &Bs[BUF][b_dst[i]]);                     \
    SB0;                                                                   \
  } while (0)
#define RD_A(DST, KK, MIG, AB)                                             \
  do { SB0;                                                                \
    _Pragma("unroll") for (int mi = 0; mi < 4; ++mi)                       \
      DST[mi] = *(const bf16x8*)((AB) + abase + ((MIG)*4 + mi) * 1024 +    \
                                 ((KK) ? axk1 : axk0));                    \
    SB0;                                                                   \
  } while (0)
#define RD_B(DST, KK, BB)                                                  \
  do { SB0;                                                                \
    _Pragma("unroll") for (int nj = 0; nj < 4; ++nj)                       \
      DST[nj] = *(const bf16x8*)((BB) + bbase + nj * 1024 +                \
                                 ((KK) ? axk1 : axk0));                    \
    SB0;                                                                   \
  } while (0)
#define MFMA16(MIG, AF, BF)                                                \
  do { __builtin_amdgcn_s_setprio(1);                                      \
    _Pragma("unroll") for (int mi = 0; mi < 4; ++mi)                       \
      _Pragma("unroll") for (int nj = 0; nj < 4; ++nj)                     \
        acc[(MIG)*4 + mi][nj] = __builtin_amdgcn_mfma_f32_16x16x32_bf16(   \
            AF[mi], BF[nj], acc[(MIG)*4 + mi][nj], 0, 0, 0);               \
    __builtin_amdgcn_s_setprio(0);                                         \
  } while (0)

  // One steady tile; CU/NX are LITERAL buffer indices (compile-time).
#define BODY(TT, CU, NX)                                                   \
  do {                                                                     \
    /* PH1 (kk0,m0): issue a1 <- (kk0,m1); B(t+1) DMA */                   \
    RD_A(a1F, 0, 1, As[CU]);     /* lgkm [a0:4, b0:4, a1:4] */             \
    DMA_B4(((TT) + 1) * BK, NX); /* vm [A(t+1):8, B(t+1):4] */             \
    WLG(4);                      /* retire a0,b0 */                        \
    MFMA16(0, a0F, b0F);                                                   \
    /* PH2 (kk0,m1): issue a0 <- (kk1,m0), b1 <- kk1; A regs -> h1 */      \
    RD_A(a0F, 1, 0, As[CU]);                                               \
    RD_B(b1F, 1, Bs[CU]);        /* lgkm [a1:4, a0:4, b1:4] */             \
    WVM(4);                      /* retire A(t+1) x8 */                    \
    WR_AH(NX, 0);                /* lgkm [a1, a0, b1, w2] */               \
    WLG(10);                     /* retire a1 */                           \
    MFMA16(1, a1F, b0F);                                                   \
    /* PH3 (kk1,m0): write h2; issue a1 <- (kk1,m1); issue A(t+2) */       \
    WR_AH(NX, 1);                /* lgkm [a0, b1, w2, w2] */               \
    RD_A(a1F, 1, 1, As[CU]);     /* lgkm [a0, b1, w2, w2, a1] */           \
    LD_A8(((TT) + 2) * BK);      /* vm [B(t+1):4, A(t+2):8] */             \
    WLG(4);                      /* retire a0,b1,all writes; a1 stays */   \
    MFMA16(0, a0F, b1F);                                                   \
    WVM(8);                      /* retire B(t+1) AFTER MFMA, pre-BAR */   \
    BAR;                         /* publish NX (sole barrier per tile) */  \
    /* PH4 (kk1,m1): next tile's a0,b0 from NX; no trailing barrier */     \
    RD_A(a0F, 0, 0, As[NX]);                                               \
    RD_B(b0F, 0, Bs[NX]);        /* lgkm [a1:4, a0:4, b0:4] */             \
    WLG(8);                      /* retire a1 */                           \
    MFMA16(1, a1F, b1F);                                                   \
  } while (0)

  // ---- prologue ----
  LD_A8(0);                      // A(0) x8 vm
  WVM(0);
  WR_AH(0, 0); WR_AH(0, 1);      // A(0) -> buf0 (4w)
  DMA_B4(0, 0);                  // B(0) x4 vm
  LD_A8(BK);                     // A(1) x8 vm -> [B(0):4, A(1):8]
  WVM(8);                        // retire B(0)
  WLG(0);                        // drain A(0) writes
  BAR;                           // publish buf0
  RD_A(a0F, 0, 0, As[0]);        // lgkm [a0:4]
  RD_B(b0F, 0, Bs[0]);           // lgkm [a0:4, b0:4]
  // invariant: lgkm [a0:4, b0:4]; vm [A(t+1):8]

  // ---- steady: 62 tiles = 31 double-iterations, literal buffers ----
  for (int tt = 0; tt <= NT - 4; tt += 2) {
    BODY(tt, 0, 1);
    BODY(tt + 1, 1, 0);
  }

  // ---- tile NT-2 (cur=0, nxt=1): steady minus LD_A8; keeps tail bars ----
  {
    RD_A(a1F, 0, 1, As[0]);
    DMA_B4((NT - 1) * BK, 1);
    WLG(4);
    MFMA16(0, a0F, b0F);
    RD_A(a0F, 1, 0, As[0]);
    RD_B(b1F, 1, Bs[0]);
    WVM(4);                      // retire A(NT-1) x8
    WR_AH(1, 0);
    WLG(10);
    MFMA16(1, a1F, b0F);
    WR_AH(1, 1);
    RD_A(a1F, 1, 1, As[0]);
    WVM(0);                      // retire B(NT-1) (nothing else in flight)
    WLG(4);
    MFMA16(0, a0F, b1F);
    BAR;                         // publish
    RD_A(a0F, 0, 0, As[1]);
    RD_B(b0F, 0, Bs[1]);
    WLG(8);
    MFMA16(1, a1F, b1F);
    BAR;
  }
  // ---- tile NT-1 (cur=1): pure compute ----
  {
    RD_A(a1F, 0, 1, As[1]);
    WLG(4);
    MFMA16(0, a0F, b0F);
    RD_A(a0F, 1, 0, As[1]);
    RD_B(b1F, 1, Bs[1]);
    WLG(8);
    MFMA16(1, a1F, b0F);
    RD_A(a1F, 1, 1, As[1]);
    WLG(4);
    MFMA16(0, a0F, b1F);
    WLG(0);
    MFMA16(1, a1F, b1F);
  }

  // ---- epilogue: + sign(bias); D frag: col = l&15, row = (l>>4)*4 + j ----
#pragma unroll
  for (int ni = 0; ni < 4; ++ni) {
    const int col = n0 + wn * 64 + ni * 16 + (l & 15);
    const float b  = bias[col];
    const float bs = (b > 0.f) ? 1.f : ((b < 0.f) ? -1.f : 0.f);
#pragma unroll
    for (int mi = 0; mi < 8; ++mi) {
      const int row = m0 + wm * 128 + mi * 16 + ((l >> 4) << 2);
#pragma unroll
      for (int j = 0; j < 4; ++j)
        Z[(size_t)(row + j) * N_DIM + col] = acc[mi][ni][j] + bs;
    }
  }
#undef SB0
#undef BAR
#undef WVM
#undef WLG
#undef LD_A8
#undef WR_AH
#undef DMA_B4
#undef RD_A
#undef RD_B
#undef MFMA16
#undef BODY
}

// ---------- slow-but-correct fallback ----------
__global__ __launch_bounds__(256) void naive_fb(
    const float* __restrict__ X, const float* __restrict__ W,
    const float* __restrict__ bias, float* __restrict__ Z) {
  const size_t id = (size_t)blockIdx.x * 256 + threadIdx.x;
  const int m = (int)(id >> 10), n = (int)(id & 1023);
  float acc = 0.f;
  for (int k = 0; k < K_DIM; ++k) {
    const float w = W[(size_t)k * N_DIM + n];
    const float s = (w > 0.f) ? 1.f : ((w < 0.f) ? -1.f : 0.f);
    acc += X[(size_t)m * K_DIM + k] * s;
  }
  const float b = bias[n];
  Z[id] = acc + ((b > 0.f) ? 1.f : ((b < 0.f) ? -1.f : 0.f));
}

extern "C" void kernel_launch(void* const* d_in, const int* in_sizes, int n_in,
                              void* d_out, int out_size, void* d_ws, size_t ws_size,
                              hipStream_t stream) {
  const float* X    = (const float*)d_in[0];
  const float* W    = (const float*)d_in[1];
  const float* bias = (const float*)d_in[2];
  float* Z = (float*)d_out;

  const size_t needW = (size_t)N_DIM * K_DIM * sizeof(unsigned short);  // 8 MiB
  if (ws_size >= needW) {
    unsigned short* WbT = (unsigned short*)d_ws;
    wsign_transpose<<<dim3((K_DIM / 64) * (N_DIM / 64)), dim3(256), 0, stream>>>(W, WbT);
    gemm_r17<<<dim3((M_DIM / BM) * (N_DIM / BN)), dim3(512), 0, stream>>>(X, WbT, bias, Z);
  } else {
    naive_fb<<<dim3((size_t)M_DIM * N_DIM / 256), dim3(256), 0, stream>>>(X, W, bias, Z);
  }
}

// Round 18
// 171.088 us; speedup vs baseline: 1.5621x; 1.5621x over previous
//
#include <hip/hip_runtime.h>

#define M_DIM 16384
#define N_DIM 1024
#define K_DIM 4096

#define BM 256
#define BN 256
#define BK 64
#define NT (K_DIM / BK)

typedef __attribute__((ext_vector_type(4))) float f32x4;
typedef __attribute__((ext_vector_type(8))) short bf16x8;
typedef __attribute__((ext_vector_type(8))) unsigned short u16x8;

static __device__ __forceinline__ short f2bf(float f) {
  union { __bf16 h; short s; } u;
  u.h = (__bf16)f;   // RNE; pairs pack into v_cvt_pk_bf16_f32
  return u.s;
}

static __device__ __forceinline__ void load_lds16(const void* g, void* l) {
  __builtin_amdgcn_global_load_lds(
      (const __attribute__((address_space(1))) void*)g,
      (__attribute__((address_space(3))) void*)l, 16, 0, 0);
}

// ---------- prepass: WbT[n][k] = bf16(sign(W[k][n])) ----------
// Row stride 70 u16 (35 dwords): column reads split across 2 bank sets,
// worst 2-way alias (free, m136).
__global__ __launch_bounds__(256) void wsign_transpose(
    const float* __restrict__ W, unsigned short* __restrict__ WbT) {
  __shared__ unsigned short tile[64][70];
  const int t  = (int)threadIdx.x;
  const int k0 = (int)(blockIdx.x >> 4) * 64;
  const int n0 = (int)(blockIdx.x & 15) * 64;
#pragma unroll
  for (int p = 0; p < 4; ++p) {
    const int r = p * 16 + (t >> 4);
    const int c = (t & 15) * 4;
    const float* src = W + (size_t)(k0 + r) * N_DIM + n0 + c;
#pragma unroll
    for (int j = 0; j < 4; ++j) {
      const float w = src[j];
      tile[r][c + j] = (w > 0.f) ? (unsigned short)0x3F80u
                                 : ((w < 0.f) ? (unsigned short)0xBF80u
                                              : (unsigned short)0u);
    }
  }
  __syncthreads();
  const int n  = t >> 2;
  const int kg = (t & 3) * 16;
  u16x8 o0, o1;
#pragma unroll
  for (int j = 0; j < 8; ++j) o0[j] = tile[kg + j][n];
#pragma unroll
  for (int j = 0; j < 8; ++j) o1[j] = tile[kg + 8 + j][n];
  unsigned short* dst = WbT + (size_t)(n0 + n) * K_DIM + k0 + kg;
  *(u16x8*)dst       = o0;
  *(u16x8*)(dst + 8) = o1;
}

// ---------- main GEMM: R16 champion — counted-lgkm pipeline, 1 barrier/tile ----------
// Each phase issues the NEXT quadrant's ds_reads; MFMA waits on a COUNTED
// lgkm that retires only the prior batch. Single publish barrier per tile
// (PH4 anti-overwrite barrier removed; audit in R16).
__global__ __launch_bounds__(512, 2) void gemm_r9(
    const float* __restrict__ X, const unsigned short* __restrict__ WbT,
    const float* __restrict__ bias, float* __restrict__ Z) {
  __shared__ __align__(16) unsigned short As[2][BM * BK];  // 64 KiB
  __shared__ __align__(16) unsigned short Bs[2][BN * BK];  // 64 KiB

  const int t   = (int)threadIdx.x;
  const int l   = t & 63;
  const int wid = t >> 6;
  const int wm  = wid >> 2;  // 0..1
  const int wn  = wid & 3;   // 0..3

  const int bid = (int)blockIdx.x;
  const int swz = (bid & 7) * 32 + (bid >> 3);  // bijective: 256 = 8*32
  const int m0  = (swz >> 2) * BM;
  const int n0  = (swz & 3) * BN;

  const int abase = (wm * 128 + (l & 15)) * BK;
  const int bbase = (wn * 64 + (l & 15)) * BK;
  const int axk0  = (((l >> 4) + 0) ^ (l & 7)) << 3;
  const int axk1  = (((l >> 4) + 4) ^ (l & 7)) << 3;

  // A staging: thread owns rows {i*64 + t>>3}, k-granule t&7
  const float* sA0 = X + (size_t)(m0 +   0 + (t >> 3)) * K_DIM + (t & 7) * 8;
  const float* sA1 = X + (size_t)(m0 +  64 + (t >> 3)) * K_DIM + (t & 7) * 8;
  const float* sA2 = X + (size_t)(m0 + 128 + (t >> 3)) * K_DIM + (t & 7) * 8;
  const float* sA3 = X + (size_t)(m0 + 192 + (t >> 3)) * K_DIM + (t & 7) * 8;
  const int adst = (t >> 3) * BK + (((t & 7) ^ ((t >> 3) & 7)) << 3);

  // B staging: linear LDS dest, inverse-swizzled global source
  const unsigned short* b_src[4];
  int b_dst[4];
#pragma unroll
  for (int i = 0; i < 4; ++i) {
    const int c = i * 512 + t;
    const int n = c >> 3, gp = c & 7;
    b_src[i] = WbT + (size_t)(n0 + n) * K_DIM + (gp ^ (n & 7)) * 8;
    b_dst[i] = c * 8;
  }

  f32x4 acc[8][4] = {};      // 128 acc regs
  f32x4 ar[4][2];            // A(t+1) staging (32)
  bf16x8 a0F[4], a1F[4];     // ping/pong A frags (16+16)
  bf16x8 b0F[4], b1F[4];     // kk0 / kk1 B frags (16+16)

#define SB0 __builtin_amdgcn_sched_barrier(0)
#define BAR do { SB0; __builtin_amdgcn_s_barrier(); SB0; } while (0)
#define WVM(N) do { asm volatile("s_waitcnt vmcnt(" #N ")" ::: "memory"); SB0; } while (0)
#define WLG(N) do { asm volatile("s_waitcnt lgkmcnt(" #N ")" ::: "memory"); SB0; } while (0)

#define LD_A8(KT)                                                          \
  do { SB0;                                                                \
    ar[0][0] = *(const f32x4*)(sA0 + (KT));                                \
    ar[0][1] = *(const f32x4*)(sA0 + (KT) + 4);                            \
    ar[1][0] = *(const f32x4*)(sA1 + (KT));                                \
    ar[1][1] = *(const f32x4*)(sA1 + (KT) + 4);                            \
    ar[2][0] = *(const f32x4*)(sA2 + (KT));                                \
    ar[2][1] = *(const f32x4*)(sA2 + (KT) + 4);                            \
    ar[3][0] = *(const f32x4*)(sA3 + (KT));                                \
    ar[3][1] = *(const f32x4*)(sA3 + (KT) + 4); SB0;                       \
  } while (0)
#define WR_AH(BUF, H)                                                      \
  do { SB0;                                                                \
    _Pragma("unroll") for (int j = 2 * (H); j < 2 * (H) + 2; ++j) {        \
      u16x8 v;                                                             \
      _Pragma("unroll") for (int q = 0; q < 4; ++q) {                      \
        v[q]     = (unsigned short)f2bf(ar[j][0][q]);                      \
        v[4 + q] = (unsigned short)f2bf(ar[j][1][q]);                      \
      }                                                                    \
      *(u16x8*)(&As[BUF][adst + j * 4096]) = v;                            \
    } SB0;                                                                 \
  } while (0)
#define DMA_B4(KT, BUF)                                                    \
  do { SB0;                                                                \
    _Pragma("unroll") for (int i = 0; i < 4; ++i)                          \
      load_lds16(b_src[i] + (KT), &Bs[BUF][b_dst[i]]);                     \
    SB0;                                                                   \
  } while (0)
#define RD_A(DST, KK, MIG, AB)                                             \
  do { SB0;                                                                \
    _Pragma("unroll") for (int mi = 0; mi < 4; ++mi)                       \
      DST[mi] = *(const bf16x8*)((AB) + abase + ((MIG)*4 + mi) * 1024 +    \
                                 ((KK) ? axk1 : axk0));                    \
    SB0;                                                                   \
  } while (0)
#define RD_B(DST, KK, BB)                                                  \
  do { SB0;                                                                \
    _Pragma("unroll") for (int nj = 0; nj < 4; ++nj)                       \
      DST[nj] = *(const bf16x8*)((BB) + bbase + nj * 1024 +                \
                                 ((KK) ? axk1 : axk0));                    \
    SB0;                                                                   \
  } while (0)
#define MFMA16(MIG, AF, BF)                                                \
  do { __builtin_amdgcn_s_setprio(1);                                      \
    _Pragma("unroll") for (int mi = 0; mi < 4; ++mi)                       \
      _Pragma("unroll") for (int nj = 0; nj < 4; ++nj)                     \
        acc[(MIG)*4 + mi][nj] = __builtin_amdgcn_mfma_f32_16x16x32_bf16(   \
            AF[mi], BF[nj], acc[(MIG)*4 + mi][nj], 0, 0, 0);               \
    __builtin_amdgcn_s_setprio(0);                                         \
  } while (0)

  // ---- prologue ----
  LD_A8(0);                      // A(0) x8 vm
  WVM(0);
  WR_AH(0, 0); WR_AH(0, 1);      // A(0) -> buf0 (4w)
  DMA_B4(0, 0);                  // B(0) x4 vm
  LD_A8(BK);                     // A(1) x8 vm -> [B(0):4, A(1):8]
  WVM(8);                        // retire B(0)
  WLG(0);                        // drain A(0) writes
  BAR;                           // publish buf0
  RD_A(a0F, 0, 0, As[0]);        // lgkm [a0:4]
  RD_B(b0F, 0, Bs[0]);           // lgkm [a0:4, b0:4]
  // invariant: lgkm [a0:4, b0:4]; vm [A(t+1):8]

  // ---- steady: tt = 0 .. NT-3 ----
  for (int tt = 0; tt <= NT - 3; ++tt) {
    const int cur = tt & 1, nxt = cur ^ 1;
    const unsigned short* Ab = As[cur];
    const unsigned short* Bb = Bs[cur];
    // PH1 (kk0,m0): issue a1 <- (kk0,m1); B(t+1) DMA
    RD_A(a1F, 0, 1, Ab);         // lgkm [a0:4, b0:4, a1:4]
    DMA_B4((tt + 1) * BK, nxt);  // vm [A(t+1):8, B(t+1):4]
    WLG(4);                      // retire a0,b0
    MFMA16(0, a0F, b0F);
    // PH2 (kk0,m1): issue a0 <- (kk1,m0), b1 <- kk1; A(t+1) regs -> h1
    RD_A(a0F, 1, 0, Ab);
    RD_B(b1F, 1, Bb);            // lgkm [a1:4, a0:4, b1:4]
    WVM(4);                      // retire A(t+1) x8
    WR_AH(nxt, 0);               // lgkm [a1, a0, b1, w2]
    WLG(10);                     // retire a1
    MFMA16(1, a1F, b0F);
    // PH3 (kk1,m0): write h2; issue a1 <- (kk1,m1); issue A(t+2); publish
    WR_AH(nxt, 1);               // lgkm [a0, b1, w2, w2]
    RD_A(a1F, 1, 1, Ab);         // lgkm [a0, b1, w2, w2, a1]
    LD_A8((tt + 2) * BK);        // vm [B(t+1):4, A(t+2):8]
    WVM(8);                      // retire B(t+1) (publish requirement)
    WLG(4);                      // retire a0,b1,all writes; a1 stays
    MFMA16(0, a0F, b1F);
    BAR;                         // publish nxt (sole barrier per tile)
    // PH4 (kk1,m1): issue next tile's a0,b0 from nxt; NO trailing barrier
    RD_A(a0F, 0, 0, As[nxt]);
    RD_B(b0F, 0, Bs[nxt]);       // lgkm [a1:4, a0:4, b0:4]
    WLG(8);                      // retire a1
    MFMA16(1, a1F, b1F);
  }

  // ---- tile NT-2: steady minus LD_A8 (tail keeps both barriers) ----
  {
    const int cur = (NT - 2) & 1, nxt = cur ^ 1;
    const unsigned short* Ab = As[cur];
    const unsigned short* Bb = Bs[cur];
    RD_A(a1F, 0, 1, Ab);
    DMA_B4((NT - 1) * BK, nxt);
    WLG(4);
    MFMA16(0, a0F, b0F);
    RD_A(a0F, 1, 0, Ab);
    RD_B(b1F, 1, Bb);
    WVM(4);                      // retire A(NT-1) x8
    WR_AH(nxt, 0);
    WLG(10);
    MFMA16(1, a1F, b0F);
    WR_AH(nxt, 1);
    RD_A(a1F, 1, 1, Ab);
    WVM(0);                      // retire B(NT-1) (nothing else in flight)
    WLG(4);
    MFMA16(0, a0F, b1F);
    BAR;                         // publish
    RD_A(a0F, 0, 0, As[nxt]);
    RD_B(b0F, 0, Bs[nxt]);
    WLG(8);
    MFMA16(1, a1F, b1F);
    BAR;
  }
  // ---- tile NT-1: pure compute ----
  {
    const unsigned short* Ab = As[(NT - 1) & 1];
    const unsigned short* Bb = Bs[(NT - 1) & 1];
    RD_A(a1F, 0, 1, Ab);
    WLG(4);
    MFMA16(0, a0F, b0F);
    RD_A(a0F, 1, 0, Ab);
    RD_B(b1F, 1, Bb);
    WLG(8);
    MFMA16(1, a1F, b0F);
    RD_A(a1F, 1, 1, Ab);
    WLG(4);
    MFMA16(0, a0F, b1F);
    WLG(0);
    MFMA16(1, a1F, b1F);
  }

  // ---- epilogue: + sign(bias); D frag: col = l&15, row = (l>>4)*4 + j ----
#pragma unroll
  for (int ni = 0; ni < 4; ++ni) {
    const int col = n0 + wn * 64 + ni * 16 + (l & 15);
    const float b  = bias[col];
    const float bs = (b > 0.f) ? 1.f : ((b < 0.f) ? -1.f : 0.f);
#pragma unroll
    for (int mi = 0; mi < 8; ++mi) {
      const int row = m0 + wm * 128 + mi * 16 + ((l >> 4) << 2);
#pragma unroll
      for (int j = 0; j < 4; ++j)
        Z[(size_t)(row + j) * N_DIM + col] = acc[mi][ni][j] + bs;
    }
  }
#undef SB0
#undef BAR
#undef WVM
#undef WLG
#undef LD_A8
#undef WR_AH
#undef DMA_B4
#undef RD_A
#undef RD_B
#undef MFMA16
}

// ---------- slow-but-correct fallback ----------
__global__ __launch_bounds__(256) void naive_fb(
    const float* __restrict__ X, const float* __restrict__ W,
    const float* __restrict__ bias, float* __restrict__ Z) {
  const size_t id = (size_t)blockIdx.x * 256 + threadIdx.x;
  const int m = (int)(id >> 10), n = (int)(id & 1023);
  float acc = 0.f;
  for (int k = 0; k < K_DIM; ++k) {
    const float w = W[(size_t)k * N_DIM + n];
    const float s = (w > 0.f) ? 1.f : ((w < 0.f) ? -1.f : 0.f);
    acc += X[(size_t)m * K_DIM + k] * s;
  }
  const float b = bias[n];
  Z[id] = acc + ((b > 0.f) ? 1.f : ((b < 0.f) ? -1.f : 0.f));
}

extern "C" void kernel_launch(void* const* d_in, const int* in_sizes, int n_in,
                              void* d_out, int out_size, void* d_ws, size_t ws_size,
                              hipStream_t stream) {
  const float* X    = (const float*)d_in[0];
  const float* W    = (const float*)d_in[1];
  const float* bias = (const float*)d_in[2];
  float* Z = (float*)d_out;

  const size_t needW = (size_t)N_DIM * K_DIM * sizeof(unsigned short);  // 8 MiB
  if (ws_size >= needW) {
    unsigned short* WbT = (unsigned short*)d_ws;
    wsign_transpose<<<dim3((K_DIM / 64) * (N_DIM / 64)), dim3(256), 0, stream>>>(W, WbT);
    gemm_r9<<<dim3((M_DIM / BM) * (N_DIM / BN)), dim3(512), 0, stream>>>(X, WbT, bias, Z);
  } else {
    naive_fb<<<dim3((size_t)M_DIM * N_DIM / 256), dim3(256), 0, stream>>>(X, W, bias, Z);
  }
}